// Round 1
// baseline (2925.525 us; speedup 1.0000x reference)
//
#include <hip/hip_runtime.h>
#include <hip/hip_bf16.h>

// ---------------------------------------------------------------------------
// GraphSAGE distance estimator, fp32.
// Pipeline per encoder:
//   CSR build (hist -> scan -> fill), then
//   Y1 = x@Wl1 ; A1 = segmean(Y1) ; H1 = relu(A1 + bl1 + x@Wr1)
//   Y2 = H1@Wl2; A2 = segmean(Y2) ; H2 = relu(A2 + bl2 + H1@Wr2)
//   pooled[b] += H2 (atomic), cnt[b]++
// Final: depth-norm + [S|G|d] @ W1 -> relu -> @ W2.
// ---------------------------------------------------------------------------

__global__ __launch_bounds__(256) void hist_kernel(const int* __restrict__ dst,
                                                   int* __restrict__ cnt, int E) {
    int e = blockIdx.x * 256 + threadIdx.x;
    if (e < E) atomicAdd(&cnt[dst[e]], 1);
}

__global__ __launch_bounds__(1024) void scan_kernel(const int* __restrict__ cnt,
                                                    int* __restrict__ row_start,
                                                    int* __restrict__ cursor, int n) {
    __shared__ int lds[1024];
    const int t = threadIdx.x;
    const int C = (n + 1023) >> 10;
    int lo = t * C; if (lo > n) lo = n;
    int hi = lo + C; if (hi > n) hi = n;
    int s = 0;
    for (int i = lo; i < hi; ++i) s += cnt[i];
    lds[t] = s;
    __syncthreads();
    for (int off = 1; off < 1024; off <<= 1) {
        int v = (t >= off) ? lds[t - off] : 0;
        __syncthreads();
        lds[t] += v;
        __syncthreads();
    }
    int run = lds[t] - s;  // exclusive prefix
    for (int i = lo; i < hi; ++i) {
        row_start[i] = run;
        cursor[i] = run;
        run += cnt[i];
    }
    if (t == 1023) row_start[n] = lds[1023];
}

__global__ __launch_bounds__(256) void fill_kernel(const int* __restrict__ src,
                                                   const int* __restrict__ dst,
                                                   int* __restrict__ cursor,
                                                   int* __restrict__ csr, int E) {
    int e = blockIdx.x * 256 + threadIdx.x;
    if (e < E) {
        int p = atomicAdd(&cursor[dst[e]], 1);
        csr[p] = src[e];
    }
}

// out[r][j] = (relu?)( sum_k x[r][k]*W[k][j] + bias[j] + addv[r][j] )
// Block = 256 threads = 4 waves; each wave computes 4 rows; 16-row x tile + W in LDS.
template <int K>
__global__ __launch_bounds__(256) void gemm_rowwave(const float* __restrict__ x,
                                                    const float* __restrict__ W,
                                                    const float* __restrict__ addv,
                                                    const float* __restrict__ bias,
                                                    int do_relu,
                                                    float* __restrict__ out, int n) {
    __shared__ float ldsW[K * 64];
    __shared__ float ldsX[16 * K];
    const int tid = threadIdx.x;
    const int wid = tid >> 6;
    const int lane = tid & 63;
    {
        const float4* Wv = (const float4*)W;
        float4* Lv = (float4*)ldsW;
        for (int i = tid; i < K * 16; i += 256) Lv[i] = Wv[i];
    }
    const float bv = bias ? bias[lane] : 0.0f;
    __syncthreads();

    const int KC = K / 4;
    for (int base = blockIdx.x * 16; base < n; base += gridDim.x * 16) {
        {
            const float4* xv = (const float4*)(x + (size_t)base * K);
            float4* lx = (float4*)ldsX;
            int vrows = n - base; if (vrows > 16) vrows = 16;
            const int valid4 = vrows * KC;
            for (int i = tid; i < 16 * KC; i += 256)
                if (i < valid4) lx[i] = xv[i];
        }
        __syncthreads();
        float acc0 = 0.f, acc1 = 0.f, acc2 = 0.f, acc3 = 0.f;
        const float4* lxv = (const float4*)ldsX;
        #pragma unroll 4
        for (int kc = 0; kc < KC; ++kc) {
            const float w0 = ldsW[(kc * 4 + 0) * 64 + lane];
            const float w1 = ldsW[(kc * 4 + 1) * 64 + lane];
            const float w2 = ldsW[(kc * 4 + 2) * 64 + lane];
            const float w3 = ldsW[(kc * 4 + 3) * 64 + lane];
            const float4 x0 = lxv[(wid * 4 + 0) * KC + kc];
            const float4 x1 = lxv[(wid * 4 + 1) * KC + kc];
            const float4 x2 = lxv[(wid * 4 + 2) * KC + kc];
            const float4 x3 = lxv[(wid * 4 + 3) * KC + kc];
            acc0 += x0.x * w0 + x0.y * w1 + x0.z * w2 + x0.w * w3;
            acc1 += x1.x * w0 + x1.y * w1 + x1.z * w2 + x1.w * w3;
            acc2 += x2.x * w0 + x2.y * w1 + x2.z * w2 + x2.w * w3;
            acc3 += x3.x * w0 + x3.y * w1 + x3.z * w2 + x3.w * w3;
        }
        const int r = base + wid * 4;
        float accs[4] = {acc0, acc1, acc2, acc3};
        #pragma unroll
        for (int rr = 0; rr < 4; ++rr) {
            const int row = r + rr;
            if (row < n) {
                float v = accs[rr] + bv;
                if (addv) v += addv[(size_t)row * 64 + lane];
                if (do_relu) v = fmaxf(v, 0.0f);
                out[(size_t)row * 64 + lane] = v;
            }
        }
        __syncthreads();
    }
}

// Wave per destination node: lane j accumulates feature j over the CSR edge list.
__global__ __launch_bounds__(256) void agg_mean(const float* __restrict__ Y,
                                                const int* __restrict__ csr,
                                                const int* __restrict__ row_start,
                                                float* __restrict__ out, int n) {
    const int wid = threadIdx.x >> 6;
    const int lane = threadIdx.x & 63;
    for (int i = blockIdx.x * 4 + wid; i < n; i += gridDim.x * 4) {
        int r0 = __builtin_amdgcn_readfirstlane(row_start[i]);
        int r1 = __builtin_amdgcn_readfirstlane(row_start[i + 1]);
        float a0 = 0.f, a1 = 0.f, a2 = 0.f, a3 = 0.f;
        int e = r0;
        for (; e + 4 <= r1; e += 4) {
            const int s0 = csr[e], s1 = csr[e + 1], s2 = csr[e + 2], s3 = csr[e + 3];
            a0 += Y[(size_t)s0 * 64 + lane];
            a1 += Y[(size_t)s1 * 64 + lane];
            a2 += Y[(size_t)s2 * 64 + lane];
            a3 += Y[(size_t)s3 * 64 + lane];
        }
        for (; e < r1; ++e) a0 += Y[(size_t)csr[e] * 64 + lane];
        const float acc = (a0 + a1) + (a2 + a3);
        const int c = r1 - r0;
        const float sc = (c > 0) ? (1.0f / (float)c) : 1.0f;
        out[(size_t)i * 64 + lane] = acc * sc;
    }
}

__global__ __launch_bounds__(256) void pool_kernel(const float* __restrict__ H,
                                                   const int* __restrict__ batch,
                                                   float* __restrict__ pooled,
                                                   int* __restrict__ pcnt, int n) {
    const int wid = threadIdx.x >> 6;
    const int lane = threadIdx.x & 63;
    for (int i = blockIdx.x * 4 + wid; i < n; i += gridDim.x * 4) {
        const int b = batch[i];
        atomicAdd(&pooled[(size_t)b * 64 + lane], H[(size_t)i * 64 + lane]);
        if (lane == 0) atomicAdd(&pcnt[b], 1);
    }
}

__global__ __launch_bounds__(128) void final_mlp(const float* __restrict__ pooledS,
                                                 const int* __restrict__ cntS,
                                                 const float* __restrict__ pooledG,
                                                 const int* __restrict__ cntG,
                                                 const float* __restrict__ depth,
                                                 const float* __restrict__ W1,
                                                 const float* __restrict__ b1,
                                                 const float* __restrict__ W2,
                                                 const float* __restrict__ b2,
                                                 float* __restrict__ out, int Bn) {
    __shared__ float lW1[129 * 64];
    __shared__ float red[128];
    const int t = threadIdx.x;
    for (int i = t; i < 129 * 64; i += 128) lW1[i] = W1[i];
    const float d = (t < Bn) ? depth[t] : 0.0f;
    red[t] = d;
    __syncthreads();
    for (int off = 64; off > 0; off >>= 1) {
        if (t < off) red[t] += red[t + off];
        __syncthreads();
    }
    const float mean = red[0] / (float)Bn;
    __syncthreads();
    const float dev = d - mean;
    red[t] = (t < Bn) ? dev * dev : 0.0f;
    __syncthreads();
    for (int off = 64; off > 0; off >>= 1) {
        if (t < off) red[t] += red[t + off];
        __syncthreads();
    }
    const float stdv = sqrtf(red[0] / (float)Bn);
    const float dn = dev / (stdv + 1e-6f);
    if (t >= Bn) return;

    float acc[64];
    #pragma unroll
    for (int j = 0; j < 64; ++j) acc[j] = b1[j];
    int cs = cntS[t]; if (cs < 1) cs = 1;
    int cg = cntG[t]; if (cg < 1) cg = 1;
    const float invS = 1.0f / (float)cs;
    const float invG = 1.0f / (float)cg;
    const float* pS = pooledS + (size_t)t * 64;
    const float* pG = pooledG + (size_t)t * 64;
    for (int k = 0; k < 64; ++k) {
        const float fk = pS[k] * invS;
        #pragma unroll
        for (int j = 0; j < 64; ++j) acc[j] += fk * lW1[k * 64 + j];
    }
    for (int k = 0; k < 64; ++k) {
        const float fk = pG[k] * invG;
        #pragma unroll
        for (int j = 0; j < 64; ++j) acc[j] += fk * lW1[(64 + k) * 64 + j];
    }
    #pragma unroll
    for (int j = 0; j < 64; ++j) acc[j] += dn * lW1[128 * 64 + j];
    float o = b2[0];
    #pragma unroll
    for (int j = 0; j < 64; ++j) o += fmaxf(acc[j], 0.0f) * W2[j];
    out[t] = o;
}

static void run_encoder(const float* x, const int* ei, const int* batch,
                        const float* Wl1, const float* bl1, const float* Wr1,
                        const float* Wl2, const float* bl2, const float* Wr2,
                        float* bufA, float* bufB, float* bufC,
                        int* csr, int* row_start, int* cursor, int* cnt,
                        float* pooled, int* pcnt, int N, int E, hipStream_t stream) {
    const int* src = ei;
    const int* dst = ei + E;
    hipMemsetAsync(cnt, 0, (size_t)N * sizeof(int), stream);
    const int egrid = (E + 255) / 256;
    hist_kernel<<<egrid, 256, 0, stream>>>(dst, cnt, E);
    scan_kernel<<<1, 1024, 0, stream>>>(cnt, row_start, cursor, N);
    fill_kernel<<<egrid, 256, 0, stream>>>(src, dst, cursor, csr, E);
    const int g16 = (N + 15) / 16;
    const int g4 = (N + 3) / 4;
    gemm_rowwave<128><<<g16, 256, 0, stream>>>(x, Wl1, nullptr, nullptr, 0, bufA, N);
    agg_mean<<<g4, 256, 0, stream>>>(bufA, csr, row_start, bufB, N);
    gemm_rowwave<128><<<g16, 256, 0, stream>>>(x, Wr1, bufB, bl1, 1, bufC, N);
    gemm_rowwave<64><<<g16, 256, 0, stream>>>(bufC, Wl2, nullptr, nullptr, 0, bufA, N);
    agg_mean<<<g4, 256, 0, stream>>>(bufA, csr, row_start, bufB, N);
    gemm_rowwave<64><<<g16, 256, 0, stream>>>(bufC, Wr2, bufB, bl2, 1, bufA, N);
    pool_kernel<<<g4, 256, 0, stream>>>(bufA, batch, pooled, pcnt, N);
}

extern "C" void kernel_launch(void* const* d_in, const int* in_sizes, int n_in,
                              void* d_out, int out_size, void* d_ws, size_t ws_size,
                              hipStream_t stream) {
    const float* state_x     = (const float*)d_in[0];
    const int*   state_ei    = (const int*)d_in[1];
    const int*   state_batch = (const int*)d_in[2];
    const float* goal_x      = (const float*)d_in[3];
    const int*   goal_ei     = (const int*)d_in[4];
    const int*   goal_batch  = (const int*)d_in[5];
    const float* depth       = (const float*)d_in[6];
    const float* s1_Wl = (const float*)d_in[7];
    const float* s1_bl = (const float*)d_in[8];
    const float* s1_Wr = (const float*)d_in[9];
    const float* s2_Wl = (const float*)d_in[10];
    const float* s2_bl = (const float*)d_in[11];
    const float* s2_Wr = (const float*)d_in[12];
    const float* g1_Wl = (const float*)d_in[13];
    const float* g1_bl = (const float*)d_in[14];
    const float* g1_Wr = (const float*)d_in[15];
    const float* g2_Wl = (const float*)d_in[16];
    const float* g2_bl = (const float*)d_in[17];
    const float* g2_Wr = (const float*)d_in[18];
    const float* mlp_W1 = (const float*)d_in[19];
    const float* mlp_b1 = (const float*)d_in[20];
    const float* mlp_W2 = (const float*)d_in[21];
    const float* mlp_b2 = (const float*)d_in[22];

    const int N  = in_sizes[0] / 128;
    const int E  = in_sizes[1] / 2;
    const int Bn = in_sizes[6];

    char* w = (char*)d_ws;
    auto alloc = [&](size_t bytes) {
        char* p = w;
        w += (bytes + 255) & ~(size_t)255;
        return p;
    };
    float* bufA      = (float*)alloc((size_t)N * 64 * sizeof(float));
    float* bufB      = (float*)alloc((size_t)N * 64 * sizeof(float));
    float* bufC      = (float*)alloc((size_t)N * 64 * sizeof(float));
    int*   csr       = (int*)alloc((size_t)E * sizeof(int));
    int*   row_start = (int*)alloc((size_t)(N + 1) * sizeof(int));
    int*   cursor    = (int*)alloc((size_t)N * sizeof(int));
    int*   cnt       = (int*)alloc((size_t)N * sizeof(int));
    float* pooledS   = (float*)alloc((size_t)Bn * 64 * sizeof(float));
    float* pooledG   = (float*)alloc((size_t)Bn * 64 * sizeof(float));
    int*   cntS      = (int*)alloc((size_t)Bn * sizeof(int));
    int*   cntG      = (int*)alloc((size_t)Bn * sizeof(int));
    const size_t need = (size_t)(w - (char*)d_ws);
    if (need > ws_size) {  // not enough scratch: fail loudly with zeros
        hipMemsetAsync(d_out, 0, (size_t)out_size * sizeof(float), stream);
        return;
    }

    hipMemsetAsync(pooledS, 0, (size_t)Bn * 64 * sizeof(float), stream);
    hipMemsetAsync(pooledG, 0, (size_t)Bn * 64 * sizeof(float), stream);
    hipMemsetAsync(cntS, 0, (size_t)Bn * sizeof(int), stream);
    hipMemsetAsync(cntG, 0, (size_t)Bn * sizeof(int), stream);

    run_encoder(state_x, state_ei, state_batch, s1_Wl, s1_bl, s1_Wr, s2_Wl, s2_bl, s2_Wr,
                bufA, bufB, bufC, csr, row_start, cursor, cnt, pooledS, cntS, N, E, stream);
    run_encoder(goal_x, goal_ei, goal_batch, g1_Wl, g1_bl, g1_Wr, g2_Wl, g2_bl, g2_Wr,
                bufA, bufB, bufC, csr, row_start, cursor, cnt, pooledG, cntG, N, E, stream);

    final_mlp<<<1, 128, 0, stream>>>(pooledS, cntS, pooledG, cntG, depth,
                                     mlp_W1, mlp_b1, mlp_W2, mlp_b2, (float*)d_out, Bn);
}

// Round 2
// 2161.362 us; speedup vs baseline: 1.3536x; 1.3536x over previous
//
#include <hip/hip_runtime.h>
#include <hip/hip_bf16.h>

// ---------------------------------------------------------------------------
// GraphSAGE distance estimator, fp32.
// Pipeline per encoder:
//   CSR build (hist -> scan -> fill), then
//   Y1 = x@Wl1 ; A1 = segmean(Y1) ; H1 = relu(A1 + bl1 + x@Wr1)
//   Y2 = H1@Wl2; A2 = segmean(Y2) ; H2 = relu(A2 + bl2 + H1@Wr2)
//   pooled[b] = segment-sum over sorted batch (binary-searched ranges, no atomics)
// Final: depth-norm + [S|G|d] @ W1 -> relu -> @ W2.
// ---------------------------------------------------------------------------

__global__ __launch_bounds__(256) void hist_kernel(const int* __restrict__ dst,
                                                   int* __restrict__ cnt, int E) {
    int e = blockIdx.x * 256 + threadIdx.x;
    if (e < E) atomicAdd(&cnt[dst[e]], 1);
}

__global__ __launch_bounds__(1024) void scan_kernel(const int* __restrict__ cnt,
                                                    int* __restrict__ row_start,
                                                    int* __restrict__ cursor, int n) {
    __shared__ int lds[1024];
    const int t = threadIdx.x;
    const int C = (n + 1023) >> 10;
    int lo = t * C; if (lo > n) lo = n;
    int hi = lo + C; if (hi > n) hi = n;
    int s = 0;
    for (int i = lo; i < hi; ++i) s += cnt[i];
    lds[t] = s;
    __syncthreads();
    for (int off = 1; off < 1024; off <<= 1) {
        int v = (t >= off) ? lds[t - off] : 0;
        __syncthreads();
        lds[t] += v;
        __syncthreads();
    }
    int run = lds[t] - s;  // exclusive prefix
    for (int i = lo; i < hi; ++i) {
        row_start[i] = run;
        cursor[i] = run;
        run += cnt[i];
    }
    if (t == 1023) row_start[n] = lds[1023];
}

__global__ __launch_bounds__(256) void fill_kernel(const int* __restrict__ src,
                                                   const int* __restrict__ dst,
                                                   int* __restrict__ cursor,
                                                   int* __restrict__ csr, int E) {
    int e = blockIdx.x * 256 + threadIdx.x;
    if (e < E) {
        int p = atomicAdd(&cursor[dst[e]], 1);
        csr[p] = src[e];
    }
}

// out[r][j] = (relu?)( sum_k x[r][k]*W[k][j] + bias[j] + addv[r][j] )
// Block = 256 threads = 4 waves; each wave computes 4 rows; 16-row x tile + W in LDS.
template <int K>
__global__ __launch_bounds__(256) void gemm_rowwave(const float* __restrict__ x,
                                                    const float* __restrict__ W,
                                                    const float* __restrict__ addv,
                                                    const float* __restrict__ bias,
                                                    int do_relu,
                                                    float* __restrict__ out, int n) {
    __shared__ float ldsW[K * 64];
    __shared__ float ldsX[16 * K];
    const int tid = threadIdx.x;
    const int wid = tid >> 6;
    const int lane = tid & 63;
    {
        const float4* Wv = (const float4*)W;
        float4* Lv = (float4*)ldsW;
        for (int i = tid; i < K * 16; i += 256) Lv[i] = Wv[i];
    }
    const float bv = bias ? bias[lane] : 0.0f;
    __syncthreads();

    const int KC = K / 4;
    for (int base = blockIdx.x * 16; base < n; base += gridDim.x * 16) {
        {
            const float4* xv = (const float4*)(x + (size_t)base * K);
            float4* lx = (float4*)ldsX;
            int vrows = n - base; if (vrows > 16) vrows = 16;
            const int valid4 = vrows * KC;
            for (int i = tid; i < 16 * KC; i += 256)
                if (i < valid4) lx[i] = xv[i];
        }
        __syncthreads();
        float acc0 = 0.f, acc1 = 0.f, acc2 = 0.f, acc3 = 0.f;
        const float4* lxv = (const float4*)ldsX;
        #pragma unroll 4
        for (int kc = 0; kc < KC; ++kc) {
            const float w0 = ldsW[(kc * 4 + 0) * 64 + lane];
            const float w1 = ldsW[(kc * 4 + 1) * 64 + lane];
            const float w2 = ldsW[(kc * 4 + 2) * 64 + lane];
            const float w3 = ldsW[(kc * 4 + 3) * 64 + lane];
            const float4 x0 = lxv[(wid * 4 + 0) * KC + kc];
            const float4 x1 = lxv[(wid * 4 + 1) * KC + kc];
            const float4 x2 = lxv[(wid * 4 + 2) * KC + kc];
            const float4 x3 = lxv[(wid * 4 + 3) * KC + kc];
            acc0 += x0.x * w0 + x0.y * w1 + x0.z * w2 + x0.w * w3;
            acc1 += x1.x * w0 + x1.y * w1 + x1.z * w2 + x1.w * w3;
            acc2 += x2.x * w0 + x2.y * w1 + x2.z * w2 + x2.w * w3;
            acc3 += x3.x * w0 + x3.y * w1 + x3.z * w2 + x3.w * w3;
        }
        const int r = base + wid * 4;
        float accs[4] = {acc0, acc1, acc2, acc3};
        #pragma unroll
        for (int rr = 0; rr < 4; ++rr) {
            const int row = r + rr;
            if (row < n) {
                float v = accs[rr] + bv;
                if (addv) v += addv[(size_t)row * 64 + lane];
                if (do_relu) v = fmaxf(v, 0.0f);
                out[(size_t)row * 64 + lane] = v;
            }
        }
        __syncthreads();
    }
}

// Wave per destination node: lane j accumulates feature j over the CSR edge list.
__global__ __launch_bounds__(256) void agg_mean(const float* __restrict__ Y,
                                                const int* __restrict__ csr,
                                                const int* __restrict__ row_start,
                                                float* __restrict__ out, int n) {
    const int wid = threadIdx.x >> 6;
    const int lane = threadIdx.x & 63;
    for (int i = blockIdx.x * 4 + wid; i < n; i += gridDim.x * 4) {
        int r0 = __builtin_amdgcn_readfirstlane(row_start[i]);
        int r1 = __builtin_amdgcn_readfirstlane(row_start[i + 1]);
        float a0 = 0.f, a1 = 0.f, a2 = 0.f, a3 = 0.f;
        int e = r0;
        for (; e + 4 <= r1; e += 4) {
            const int s0 = csr[e], s1 = csr[e + 1], s2 = csr[e + 2], s3 = csr[e + 3];
            a0 += Y[(size_t)s0 * 64 + lane];
            a1 += Y[(size_t)s1 * 64 + lane];
            a2 += Y[(size_t)s2 * 64 + lane];
            a3 += Y[(size_t)s3 * 64 + lane];
        }
        for (; e < r1; ++e) a0 += Y[(size_t)csr[e] * 64 + lane];
        const float acc = (a0 + a1) + (a2 + a3);
        const int c = r1 - r0;
        const float sc = (c > 0) ? (1.0f / (float)c) : 1.0f;
        out[(size_t)i * 64 + lane] = acc * sc;
    }
}

// batch is SORTED: one block per graph, binary-search the row range, register
// accumulate per lane, LDS-combine 4 waves. No atomics.
__global__ __launch_bounds__(256) void pool_seg(const float* __restrict__ H,
                                                const int* __restrict__ batch,
                                                float* __restrict__ pooled,
                                                int* __restrict__ pcnt, int n) {
    const int b = blockIdx.x;
    int lo = 0, hi = n;
    while (lo < hi) { int m = (lo + hi) >> 1; if (batch[m] < b) lo = m + 1; else hi = m; }
    const int beg = lo;
    hi = n;
    while (lo < hi) { int m = (lo + hi) >> 1; if (batch[m] < b + 1) lo = m + 1; else hi = m; }
    const int end = lo;

    const int wid = threadIdx.x >> 6;
    const int lane = threadIdx.x & 63;
    float acc = 0.f;
    for (int i = beg + wid; i < end; i += 4)
        acc += H[(size_t)i * 64 + lane];
    __shared__ float part[4][64];
    part[wid][lane] = acc;
    __syncthreads();
    if (wid == 0) {
        const float s = (part[0][lane] + part[1][lane]) + (part[2][lane] + part[3][lane]);
        pooled[(size_t)b * 64 + lane] = s;
        if (lane == 0) pcnt[b] = end - beg;
    }
}

__global__ __launch_bounds__(128) void final_mlp(const float* __restrict__ pooledS,
                                                 const int* __restrict__ cntS,
                                                 const float* __restrict__ pooledG,
                                                 const int* __restrict__ cntG,
                                                 const float* __restrict__ depth,
                                                 const float* __restrict__ W1,
                                                 const float* __restrict__ b1,
                                                 const float* __restrict__ W2,
                                                 const float* __restrict__ b2,
                                                 float* __restrict__ out, int Bn) {
    __shared__ float lW1[129 * 64];
    __shared__ float red[128];
    const int t = threadIdx.x;
    for (int i = t; i < 129 * 64; i += 128) lW1[i] = W1[i];
    const float d = (t < Bn) ? depth[t] : 0.0f;
    red[t] = d;
    __syncthreads();
    for (int off = 64; off > 0; off >>= 1) {
        if (t < off) red[t] += red[t + off];
        __syncthreads();
    }
    const float mean = red[0] / (float)Bn;
    __syncthreads();
    const float dev = d - mean;
    red[t] = (t < Bn) ? dev * dev : 0.0f;
    __syncthreads();
    for (int off = 64; off > 0; off >>= 1) {
        if (t < off) red[t] += red[t + off];
        __syncthreads();
    }
    const float stdv = sqrtf(red[0] / (float)Bn);
    const float dn = dev / (stdv + 1e-6f);
    if (t >= Bn) return;

    float acc[64];
    #pragma unroll
    for (int j = 0; j < 64; ++j) acc[j] = b1[j];
    int cs = cntS[t]; if (cs < 1) cs = 1;
    int cg = cntG[t]; if (cg < 1) cg = 1;
    const float invS = 1.0f / (float)cs;
    const float invG = 1.0f / (float)cg;
    const float* pS = pooledS + (size_t)t * 64;
    const float* pG = pooledG + (size_t)t * 64;
    for (int k = 0; k < 64; ++k) {
        const float fk = pS[k] * invS;
        #pragma unroll
        for (int j = 0; j < 64; ++j) acc[j] += fk * lW1[k * 64 + j];
    }
    for (int k = 0; k < 64; ++k) {
        const float fk = pG[k] * invG;
        #pragma unroll
        for (int j = 0; j < 64; ++j) acc[j] += fk * lW1[(64 + k) * 64 + j];
    }
    #pragma unroll
    for (int j = 0; j < 64; ++j) acc[j] += dn * lW1[128 * 64 + j];
    float o = b2[0];
    #pragma unroll
    for (int j = 0; j < 64; ++j) o += fmaxf(acc[j], 0.0f) * W2[j];
    out[t] = o;
}

static void run_encoder(const float* x, const int* ei, const int* batch,
                        const float* Wl1, const float* bl1, const float* Wr1,
                        const float* Wl2, const float* bl2, const float* Wr2,
                        float* bufA, float* bufB, float* bufC,
                        int* csr, int* row_start, int* cursor, int* cnt,
                        float* pooled, int* pcnt, int N, int E, int Bn,
                        hipStream_t stream) {
    const int* src = ei;
    const int* dst = ei + E;
    hipMemsetAsync(cnt, 0, (size_t)N * sizeof(int), stream);
    const int egrid = (E + 255) / 256;
    hist_kernel<<<egrid, 256, 0, stream>>>(dst, cnt, E);
    scan_kernel<<<1, 1024, 0, stream>>>(cnt, row_start, cursor, N);
    fill_kernel<<<egrid, 256, 0, stream>>>(src, dst, cursor, csr, E);
    const int g16 = (N + 15) / 16;
    const int g4 = (N + 3) / 4;
    gemm_rowwave<128><<<g16, 256, 0, stream>>>(x, Wl1, nullptr, nullptr, 0, bufA, N);
    agg_mean<<<g4, 256, 0, stream>>>(bufA, csr, row_start, bufB, N);
    gemm_rowwave<128><<<g16, 256, 0, stream>>>(x, Wr1, bufB, bl1, 1, bufC, N);
    gemm_rowwave<64><<<g16, 256, 0, stream>>>(bufC, Wl2, nullptr, nullptr, 0, bufA, N);
    agg_mean<<<g4, 256, 0, stream>>>(bufA, csr, row_start, bufB, N);
    gemm_rowwave<64><<<g16, 256, 0, stream>>>(bufC, Wr2, bufB, bl2, 1, bufA, N);
    pool_seg<<<Bn, 256, 0, stream>>>(bufA, batch, pooled, pcnt, N);
}

extern "C" void kernel_launch(void* const* d_in, const int* in_sizes, int n_in,
                              void* d_out, int out_size, void* d_ws, size_t ws_size,
                              hipStream_t stream) {
    const float* state_x     = (const float*)d_in[0];
    const int*   state_ei    = (const int*)d_in[1];
    const int*   state_batch = (const int*)d_in[2];
    const float* goal_x      = (const float*)d_in[3];
    const int*   goal_ei     = (const int*)d_in[4];
    const int*   goal_batch  = (const int*)d_in[5];
    const float* depth       = (const float*)d_in[6];
    const float* s1_Wl = (const float*)d_in[7];
    const float* s1_bl = (const float*)d_in[8];
    const float* s1_Wr = (const float*)d_in[9];
    const float* s2_Wl = (const float*)d_in[10];
    const float* s2_bl = (const float*)d_in[11];
    const float* s2_Wr = (const float*)d_in[12];
    const float* g1_Wl = (const float*)d_in[13];
    const float* g1_bl = (const float*)d_in[14];
    const float* g1_Wr = (const float*)d_in[15];
    const float* g2_Wl = (const float*)d_in[16];
    const float* g2_bl = (const float*)d_in[17];
    const float* g2_Wr = (const float*)d_in[18];
    const float* mlp_W1 = (const float*)d_in[19];
    const float* mlp_b1 = (const float*)d_in[20];
    const float* mlp_W2 = (const float*)d_in[21];
    const float* mlp_b2 = (const float*)d_in[22];

    const int N  = in_sizes[0] / 128;
    const int E  = in_sizes[1] / 2;
    const int Bn = in_sizes[6];

    char* w = (char*)d_ws;
    auto alloc = [&](size_t bytes) {
        char* p = w;
        w += (bytes + 255) & ~(size_t)255;
        return p;
    };
    float* bufA      = (float*)alloc((size_t)N * 64 * sizeof(float));
    float* bufB      = (float*)alloc((size_t)N * 64 * sizeof(float));
    float* bufC      = (float*)alloc((size_t)N * 64 * sizeof(float));
    int*   csr       = (int*)alloc((size_t)E * sizeof(int));
    int*   row_start = (int*)alloc((size_t)(N + 1) * sizeof(int));
    int*   cursor    = (int*)alloc((size_t)N * sizeof(int));
    int*   cnt       = (int*)alloc((size_t)N * sizeof(int));
    float* pooledS   = (float*)alloc((size_t)Bn * 64 * sizeof(float));
    float* pooledG   = (float*)alloc((size_t)Bn * 64 * sizeof(float));
    int*   cntS      = (int*)alloc((size_t)Bn * sizeof(int));
    int*   cntG      = (int*)alloc((size_t)Bn * sizeof(int));
    const size_t need = (size_t)(w - (char*)d_ws);
    if (need > ws_size) {  // not enough scratch: fail loudly with zeros
        hipMemsetAsync(d_out, 0, (size_t)out_size * sizeof(float), stream);
        return;
    }

    run_encoder(state_x, state_ei, state_batch, s1_Wl, s1_bl, s1_Wr, s2_Wl, s2_bl, s2_Wr,
                bufA, bufB, bufC, csr, row_start, cursor, cnt, pooledS, cntS, N, E, Bn, stream);
    run_encoder(goal_x, goal_ei, goal_batch, g1_Wl, g1_bl, g1_Wr, g2_Wl, g2_bl, g2_Wr,
                bufA, bufB, bufC, csr, row_start, cursor, cnt, pooledG, cntG, N, E, Bn, stream);

    final_mlp<<<1, 128, 0, stream>>>(pooledS, cntS, pooledG, cntG, depth,
                                     mlp_W1, mlp_b1, mlp_W2, mlp_b2, (float*)d_out, Bn);
}